// Round 11
// baseline (46.641 us; speedup 1.0000x reference)
//
#include <hip/hip_runtime.h>

#define EDGE_EPS 1e-8f

typedef float fvec4 __attribute__((ext_vector_type(4)));   // 16B-aligned vec4

struct V3 { float x, y, z; };
struct V4 { float x, y, z, w; };

__device__ __forceinline__ V3 v3(float a, float b, float c) { V3 r{a,b,c}; return r; }

__device__ __forceinline__ V3 addv(V3 a, V3 b) { return v3(a.x+b.x, a.y+b.y, a.z+b.z); }
__device__ __forceinline__ V3 subv(V3 a, V3 b) { return v3(a.x-b.x, a.y-b.y, a.z-b.z); }
__device__ __forceinline__ V3 muls(V3 a, float s) { return v3(a.x*s, a.y*s, a.z*s); }
__device__ __forceinline__ float dotv(V3 a, V3 b) { return a.x*b.x + a.y*b.y + a.z*b.z; }
__device__ __forceinline__ V3 crossv(V3 a, V3 b) {
    return v3(a.y*b.z - a.z*b.y,
              a.z*b.x - a.x*b.z,
              a.x*b.y - a.y*b.x);
}

__device__ __forceinline__ V4 qmul(V4 a, V4 b) {
    V3 v1 = v3(a.x, a.y, a.z), v2 = v3(b.x, b.y, b.z);
    V3 c = crossv(v1, v2);
    V4 r;
    r.x = a.w*b.x + b.w*a.x + c.x;
    r.y = a.w*b.y + b.w*a.y + c.y;
    r.z = a.w*b.z + b.w*a.z + c.z;
    r.w = a.w*b.w - dotv(v1, v2);
    return r;
}

__device__ __forceinline__ V3 qact(V4 q, V3 t) {
    V3 v = v3(q.x, q.y, q.z);
    V3 inner = crossv(v, t);
    inner.x += q.w * t.x; inner.y += q.w * t.y; inner.z += q.w * t.z;
    V3 o = crossv(v, inner);
    return v3(t.x + 2.0f*o.x, t.y + 2.0f*o.y, t.z + 2.0f*o.z);
}

__device__ __forceinline__ V3 qlog(V4 q) {
    float sgn = (q.w >= 0.0f) ? 1.0f : -1.0f;
    float x = q.x * sgn, y = q.y * sgn, z = q.z * sgn, w = q.w * sgn;
    float n = sqrtf(x*x + y*y + z*z);
    float theta = 2.0f * atan2f(n, w);
    float coef = (n < EDGE_EPS) ? 2.0f : theta / fmaxf(n, EDGE_EPS);
    return v3(coef*x, coef*y, coef*z);
}

__device__ __forceinline__ V4 qinvq(V4 q) { V4 r{-q.x,-q.y,-q.z,q.w}; return r; }

__device__ __forceinline__ V3 ld3(const float* __restrict__ p, int idx) {
    return v3(p[3*idx+0], p[3*idx+1], p[3*idx+2]);
}

__global__ void __launch_bounds__(128)
swc_kernel(const float* __restrict__ R0, const float* __restrict__ t0,
           const float4* __restrict__ rot,  const float* __restrict__ trans,
           const float* __restrict__ vel,   const float* __restrict__ ba,
           const float* __restrict__ bg,    const float4* __restrict__ dRq,
           const float* __restrict__ dv,    const float* __restrict__ dp,
           const float* __restrict__ dt,    const float4* __restrict__ vRq,
           const float* __restrict__ vt,    float* __restrict__ out, int N)
{
    // A/B vs R7: identical kernel, REGULAR stores instead of non-temporal.
    __shared__ __align__(16) float obuf[64 * 27];

    const int base = blockIdx.x * 128;
    const int tid  = threadIdx.x;
    const int k    = base + tid;
    const bool active = (k < N);

    float res[27];
    if (active) {
        // ---- direct loads (R5/R7-proven path) ----
        V4 Rk; V3 tk;
        if (k == 0) {
            Rk = V4{R0[0], R0[1], R0[2], R0[3]};
            tk = v3(t0[0], t0[1], t0[2]);
        } else {
            float4 r = rot[k-1];
            Rk = V4{r.x, r.y, r.z, r.w};
            tk = ld3(trans, k-1);
        }
        float4 r1 = rot[k];
        V4 Rk1{r1.x, r1.y, r1.z, r1.w};
        float4 dr = dRq[k];  V4 dRk{dr.x, dr.y, dr.z, dr.w};
        float4 vr = vRq[k];  V4 vRk{vr.x, vr.y, vr.z, vr.w};
        float dtk = dt[k];

        V3 tk1  = ld3(trans, k);
        V3 vk   = ld3(vel, k);
        V3 vk1  = ld3(vel, k+1);    // vel/ba/bg have N+1 entries
        V3 bak  = ld3(ba, k);
        V3 bak1 = ld3(ba, k+1);
        V3 bgk  = ld3(bg, k);
        V3 bgk1 = ld3(bg, k+1);
        V3 dvk  = ld3(dv, k);
        V3 dpk  = ld3(dp, k);
        V3 vtk  = ld3(vt, k);

        // ---- math ----
        V4 Rinv = qinvq(Rk);
        V4 relR = qmul(Rinv, Rk1);
        V3 dtrans = subv(tk1, tk);
        V3 rel_t_est = qact(Rinv, dtrans);

        V3 r_rot = addv(qlog(qmul(qinvq(dRk), relR)), muls(bgk, dtk));

        V3 r_cross = qact(Rinv, subv(dtrans, muls(vk, dtk)));
        r_cross = addv(subv(r_cross, dpk), muls(bak, 0.5f*dtk*dtk));

        V3 r_deltav = addv(subv(subv(vk1, vk), qact(Rk, dvk)), muls(bak, dtk));

        V3 r_vis_rot = qlog(qmul(qinvq(vRk), relR));
        V3 r_vis_t   = subv(rel_t_est, vtk);

        res[ 0] = r_vis_rot.x; res[ 1] = r_vis_rot.y; res[ 2] = r_vis_rot.z;
        res[ 3] = r_vis_t.x;   res[ 4] = r_vis_t.y;   res[ 5] = r_vis_t.z;
        res[ 6] = r_rot.x;     res[ 7] = r_rot.y;     res[ 8] = r_rot.z;
        res[ 9] = r_cross.x;   res[10] = r_cross.y;   res[11] = r_cross.z;
        res[12] = r_deltav.x;  res[13] = r_deltav.y;  res[14] = r_deltav.z;
        res[15] = bak1.x - bak.x; res[16] = bak1.y - bak.y; res[17] = bak1.z - bak.z;
        res[18] = bgk1.x - bgk.x; res[19] = bgk1.y - bgk.y; res[20] = bgk1.z - bgk.z;
        res[21] = bak.x;       res[22] = bak.y;       res[23] = bak.z;
        res[24] = bgk.x;       res[25] = bgk.y;       res[26] = bgk.z;
    }

    const int cnt = min(128, N - base);
    if (cnt == 128) {
        // ---- half 0: edges [base, base+64) ----
        if (tid < 64) {
            #pragma unroll
            for (int r = 0; r < 27; ++r) obuf[tid * 27 + r] = res[r];
        }
        __syncthreads();
        {
            const fvec4* s4 = reinterpret_cast<const fvec4*>(obuf);
            fvec4* o4 = reinterpret_cast<fvec4*>(out + (size_t)base * 27);
            #pragma unroll
            for (int rep = 0; rep < 4; ++rep) {
                int j = tid + rep * 128;
                if (j < 432) o4[j] = s4[j];
            }
        }
        __syncthreads();
        // ---- half 1: edges [base+64, base+128) ----
        if (tid >= 64) {
            #pragma unroll
            for (int r = 0; r < 27; ++r) obuf[(tid - 64) * 27 + r] = res[r];
        }
        __syncthreads();
        {
            const fvec4* s4 = reinterpret_cast<const fvec4*>(obuf);
            fvec4* o4 = reinterpret_cast<fvec4*>(out + (size_t)(base + 64) * 27);
            #pragma unroll
            for (int rep = 0; rep < 4; ++rep) {
                int j = tid + rep * 128;
                if (j < 432) o4[j] = s4[j];
            }
        }
    } else {
        // tail block (only the last one): direct scalar stores
        if (active) {
            float* og = out + (size_t)k * 27;
            #pragma unroll
            for (int r = 0; r < 27; ++r) og[r] = res[r];
        }
    }
}

extern "C" void kernel_launch(void* const* d_in, const int* in_sizes, int n_in,
                              void* d_out, int out_size, void* d_ws, size_t ws_size,
                              hipStream_t stream) {
    const float*  R0    = (const float*)d_in[0];
    const float*  t0    = (const float*)d_in[1];
    const float4* rot   = (const float4*)d_in[2];
    const float*  trans = (const float*)d_in[3];
    const float*  vel   = (const float*)d_in[4];
    const float*  ba    = (const float*)d_in[5];
    const float*  bg    = (const float*)d_in[6];
    const float4* dRq   = (const float4*)d_in[7];
    const float*  dv    = (const float*)d_in[8];
    const float*  dp    = (const float*)d_in[9];
    const float*  dt    = (const float*)d_in[10];
    const float4* vRq   = (const float4*)d_in[11];
    const float*  vt    = (const float*)d_in[12];
    float* out = (float*)d_out;

    int N = in_sizes[2] / 4;   // rotations: (W-1, 4)
    int block = 128;
    int grid = (N + block - 1) / block;
    swc_kernel<<<grid, block, 0, stream>>>(R0, t0, rot, trans, vel, ba, bg,
                                           dRq, dv, dp, dt, vRq, vt, out, N);
}

// Round 12
// 42.643 us; speedup vs baseline: 1.0937x; 1.0937x over previous
//
#include <hip/hip_runtime.h>

#define EDGE_EPS 1e-8f

typedef float fvec4 __attribute__((ext_vector_type(4)));   // 16B-aligned vec4

struct V3 { float x, y, z; };
struct V4 { float x, y, z, w; };

__device__ __forceinline__ V3 v3(float a, float b, float c) { V3 r{a,b,c}; return r; }

__device__ __forceinline__ V3 addv(V3 a, V3 b) { return v3(a.x+b.x, a.y+b.y, a.z+b.z); }
__device__ __forceinline__ V3 subv(V3 a, V3 b) { return v3(a.x-b.x, a.y-b.y, a.z-b.z); }
__device__ __forceinline__ V3 muls(V3 a, float s) { return v3(a.x*s, a.y*s, a.z*s); }
__device__ __forceinline__ float dotv(V3 a, V3 b) { return a.x*b.x + a.y*b.y + a.z*b.z; }
__device__ __forceinline__ V3 crossv(V3 a, V3 b) {
    return v3(a.y*b.z - a.z*b.y,
              a.z*b.x - a.x*b.z,
              a.x*b.y - a.y*b.x);
}

__device__ __forceinline__ V4 qmul(V4 a, V4 b) {
    V3 v1 = v3(a.x, a.y, a.z), v2 = v3(b.x, b.y, b.z);
    V3 c = crossv(v1, v2);
    V4 r;
    r.x = a.w*b.x + b.w*a.x + c.x;
    r.y = a.w*b.y + b.w*a.y + c.y;
    r.z = a.w*b.z + b.w*a.z + c.z;
    r.w = a.w*b.w - dotv(v1, v2);
    return r;
}

__device__ __forceinline__ V3 qact(V4 q, V3 t) {
    V3 v = v3(q.x, q.y, q.z);
    V3 inner = crossv(v, t);
    inner.x += q.w * t.x; inner.y += q.w * t.y; inner.z += q.w * t.z;
    V3 o = crossv(v, inner);
    return v3(t.x + 2.0f*o.x, t.y + 2.0f*o.y, t.z + 2.0f*o.z);
}

__device__ __forceinline__ V3 qlog(V4 q) {
    float sgn = (q.w >= 0.0f) ? 1.0f : -1.0f;
    float x = q.x * sgn, y = q.y * sgn, z = q.z * sgn, w = q.w * sgn;
    float n = sqrtf(x*x + y*y + z*z);
    float theta = 2.0f * atan2f(n, w);
    float coef = (n < EDGE_EPS) ? 2.0f : theta / fmaxf(n, EDGE_EPS);
    return v3(coef*x, coef*y, coef*z);
}

__device__ __forceinline__ V4 qinvq(V4 q) { V4 r{-q.x,-q.y,-q.z,q.w}; return r; }

__device__ __forceinline__ V3 ld3(const float* __restrict__ p, int idx) {
    return v3(p[3*idx+0], p[3*idx+1], p[3*idx+2]);
}

__global__ void __launch_bounds__(128)
swc_kernel(const float* __restrict__ R0, const float* __restrict__ t0,
           const float4* __restrict__ rot,  const float* __restrict__ trans,
           const float* __restrict__ vel,   const float* __restrict__ ba,
           const float* __restrict__ bg,    const float4* __restrict__ dRq,
           const float* __restrict__ dv,    const float* __restrict__ dp,
           const float* __restrict__ dt,    const float4* __restrict__ vRq,
           const float* __restrict__ vt,    float* __restrict__ out, int N)
{
    // R7 terminal structure:
    //  - direct per-thread loads (input staging proven worthless: R2)
    //  - LDS output transpose (makes nt stores full-line: R9 showed 4.1x
    //    write amplification without it)
    //  - non-temporal dense float4 stores (+25% vs regular: R4, re-confirmed R11 A/B)
    __shared__ __align__(16) float obuf[64 * 27];   // 6912 B

    const int base = blockIdx.x * 128;
    const int tid  = threadIdx.x;
    const int k    = base + tid;
    const bool active = (k < N);

    float res[27];
    if (active) {
        // ---- direct loads ----
        V4 Rk; V3 tk;
        if (k == 0) {
            Rk = V4{R0[0], R0[1], R0[2], R0[3]};
            tk = v3(t0[0], t0[1], t0[2]);
        } else {
            float4 r = rot[k-1];
            Rk = V4{r.x, r.y, r.z, r.w};
            tk = ld3(trans, k-1);
        }
        float4 r1 = rot[k];
        V4 Rk1{r1.x, r1.y, r1.z, r1.w};
        float4 dr = dRq[k];  V4 dRk{dr.x, dr.y, dr.z, dr.w};
        float4 vr = vRq[k];  V4 vRk{vr.x, vr.y, vr.z, vr.w};
        float dtk = dt[k];

        V3 tk1  = ld3(trans, k);
        V3 vk   = ld3(vel, k);
        V3 vk1  = ld3(vel, k+1);    // vel/ba/bg have N+1 entries
        V3 bak  = ld3(ba, k);
        V3 bak1 = ld3(ba, k+1);
        V3 bgk  = ld3(bg, k);
        V3 bgk1 = ld3(bg, k+1);
        V3 dvk  = ld3(dv, k);
        V3 dpk  = ld3(dp, k);
        V3 vtk  = ld3(vt, k);

        // ---- math ----
        V4 Rinv = qinvq(Rk);
        V4 relR = qmul(Rinv, Rk1);
        V3 dtrans = subv(tk1, tk);
        V3 rel_t_est = qact(Rinv, dtrans);

        V3 r_rot = addv(qlog(qmul(qinvq(dRk), relR)), muls(bgk, dtk));

        V3 r_cross = qact(Rinv, subv(dtrans, muls(vk, dtk)));
        r_cross = addv(subv(r_cross, dpk), muls(bak, 0.5f*dtk*dtk));

        V3 r_deltav = addv(subv(subv(vk1, vk), qact(Rk, dvk)), muls(bak, dtk));

        V3 r_vis_rot = qlog(qmul(qinvq(vRk), relR));
        V3 r_vis_t   = subv(rel_t_est, vtk);

        res[ 0] = r_vis_rot.x; res[ 1] = r_vis_rot.y; res[ 2] = r_vis_rot.z;
        res[ 3] = r_vis_t.x;   res[ 4] = r_vis_t.y;   res[ 5] = r_vis_t.z;
        res[ 6] = r_rot.x;     res[ 7] = r_rot.y;     res[ 8] = r_rot.z;
        res[ 9] = r_cross.x;   res[10] = r_cross.y;   res[11] = r_cross.z;
        res[12] = r_deltav.x;  res[13] = r_deltav.y;  res[14] = r_deltav.z;
        res[15] = bak1.x - bak.x; res[16] = bak1.y - bak.y; res[17] = bak1.z - bak.z;
        res[18] = bgk1.x - bgk.x; res[19] = bgk1.y - bgk.y; res[20] = bgk1.z - bgk.z;
        res[21] = bak.x;       res[22] = bak.y;       res[23] = bak.z;
        res[24] = bgk.x;       res[25] = bgk.y;       res[26] = bgk.z;
    }

    const int cnt = min(128, N - base);
    if (cnt == 128) {
        // ---- half 0: edges [base, base+64) ----
        if (tid < 64) {
            #pragma unroll
            for (int r = 0; r < 27; ++r) obuf[tid * 27 + r] = res[r];
        }
        __syncthreads();
        {
            const fvec4* s4 = reinterpret_cast<const fvec4*>(obuf);
            fvec4* o4 = reinterpret_cast<fvec4*>(out + (size_t)base * 27);
            #pragma unroll
            for (int rep = 0; rep < 4; ++rep) {
                int j = tid + rep * 128;
                if (j < 432) __builtin_nontemporal_store(s4[j], &o4[j]);
            }
        }
        __syncthreads();
        // ---- half 1: edges [base+64, base+128) ----
        if (tid >= 64) {
            #pragma unroll
            for (int r = 0; r < 27; ++r) obuf[(tid - 64) * 27 + r] = res[r];
        }
        __syncthreads();
        {
            const fvec4* s4 = reinterpret_cast<const fvec4*>(obuf);
            fvec4* o4 = reinterpret_cast<fvec4*>(out + (size_t)(base + 64) * 27);
            #pragma unroll
            for (int rep = 0; rep < 4; ++rep) {
                int j = tid + rep * 128;
                if (j < 432) __builtin_nontemporal_store(s4[j], &o4[j]);
            }
        }
    } else {
        // tail block (only the last one): direct scalar stores, negligible volume
        if (active) {
            float* og = out + (size_t)k * 27;
            #pragma unroll
            for (int r = 0; r < 27; ++r) og[r] = res[r];
        }
    }
}

extern "C" void kernel_launch(void* const* d_in, const int* in_sizes, int n_in,
                              void* d_out, int out_size, void* d_ws, size_t ws_size,
                              hipStream_t stream) {
    const float*  R0    = (const float*)d_in[0];
    const float*  t0    = (const float*)d_in[1];
    const float4* rot   = (const float4*)d_in[2];
    const float*  trans = (const float*)d_in[3];
    const float*  vel   = (const float*)d_in[4];
    const float*  ba    = (const float*)d_in[5];
    const float*  bg    = (const float*)d_in[6];
    const float4* dRq   = (const float4*)d_in[7];
    const float*  dv    = (const float*)d_in[8];
    const float*  dp    = (const float*)d_in[9];
    const float*  dt    = (const float*)d_in[10];
    const float4* vRq   = (const float4*)d_in[11];
    const float*  vt    = (const float*)d_in[12];
    float* out = (float*)d_out;

    int N = in_sizes[2] / 4;   // rotations: (W-1, 4)
    int block = 128;
    int grid = (N + block - 1) / block;
    swc_kernel<<<grid, block, 0, stream>>>(R0, t0, rot, trans, vel, ba, bg,
                                           dRq, dv, dp, dt, vRq, vt, out, N);
}